// Round 1
// baseline (6361.691 us; speedup 1.0000x reference)
//
#include <hip/hip_runtime.h>
#include <hip/hip_fp16.h>

// LSTM autoencoder: B=256, S=512, D=64, H=128.
// Per-batch-row recurrence independence -> 128 WGs x 2 rows, no grid sync.
// f16 weights (k-major packed), v_dot2_f32_f16, fp32 state/accum.

typedef _Float16 h2 __attribute__((ext_vector_type(2)));
typedef _Float16 h4 __attribute__((ext_vector_type(4)));
typedef _Float16 h8 __attribute__((ext_vector_type(8)));

#define Bsz 256
#define Ssz 512
#define Dsz 64
#define Hsz 128
#define G4 512   // 4*H gates
#define NT 512   // threads per WG
#define RPW 2    // rows per WG
#define NWG (Bsz / RPW)

__device__ __forceinline__ float fdot2f(h2 a, h2 b, float c) {
#if __has_builtin(__builtin_amdgcn_fdot2)
  return __builtin_amdgcn_fdot2(a, b, c, false);
#else
  return c + (float)a[0] * (float)b[0] + (float)a[1] * (float)b[1];
#endif
}

__device__ __forceinline__ float dot4(h4 in, h4 w, float acc) {
  h2 il = __builtin_shufflevector(in, in, 0, 1);
  h2 ih = __builtin_shufflevector(in, in, 2, 3);
  h2 wl = __builtin_shufflevector(w, w, 0, 1);
  h2 wh = __builtin_shufflevector(w, w, 2, 3);
  return fdot2f(ih, wh, fdot2f(il, wl, acc));
}

__device__ __forceinline__ void split8(h8 v, h4& a, h4& b) {
  a = __builtin_shufflevector(v, v, 0, 1, 2, 3);
  b = __builtin_shufflevector(v, v, 4, 5, 6, 7);
}

__device__ __forceinline__ float sigm(float v) { return 1.f / (1.f + __expf(-v)); }
__device__ __forceinline__ float tanh_f(float v) { return 2.f / (1.f + __expf(-2.f * v)) - 1.f; }

// Packed LDS input layout: array of h8, entry k = [row0 k*4..k*4+3 | row1 k*4..k*4+3]
__device__ __forceinline__ int pidx(int r, int j) { return (j >> 2) * 8 + r * 4 + (j & 3); }

__global__ void __launch_bounds__(NT, 1)
enc_kernel(const float* __restrict__ x,
           const h4* __restrict__ wih0, const h4* __restrict__ whh0,
           const h4* __restrict__ wih1, const h4* __restrict__ whh1,
           const float* __restrict__ bsum0, const float* __restrict__ bsum1,
           float* __restrict__ st) {
  __shared__ h4 s_whh1[32 * G4];                    // 128 KiB LDS-resident weights
  __shared__ float g[RPW][G4];
  __shared__ float c0s[RPW][Hsz], c1s[RPW][Hsz], h0f[RPW][Hsz], h1f[RPW][Hsz];
  __shared__ h8 hp0[Hsz / 4], hp1[Hsz / 4], xp[Dsz / 4];

  const int tid = threadIdx.x;
  const int row0 = blockIdx.x * RPW;

  for (int i = tid; i < 32 * G4; i += NT) s_whh1[i] = whh1[i];
  if (tid < RPW * Hsz) {
    int r = tid >> 7, j = tid & (Hsz - 1);
    c0s[r][j] = 0.f; c1s[r][j] = 0.f; h0f[r][j] = 0.f; h1f[r][j] = 0.f;
  }
  if (tid < 256) ((_Float16*)hp0)[tid] = (_Float16)0.f;
  else ((_Float16*)hp1)[tid - 256] = (_Float16)0.f;
  const float b0 = bsum0[tid];
  const float b1 = bsum1[tid];
  __syncthreads();

  for (int t = 0; t < Ssz; ++t) {
    if (tid < RPW * Dsz) {
      int r = tid >> 6, j = tid & (Dsz - 1);
      ((_Float16*)xp)[pidx(r, j)] = (_Float16)x[((size_t)(row0 + r) * Ssz + t) * Dsz + j];
    }
    __syncthreads();
    {  // layer0 gates
      float a0 = b0, a1 = b0;
#pragma unroll
      for (int k = 0; k < Dsz / 4; ++k) {
        h4 w = wih0[k * G4 + tid];
        h4 i0, i1; split8(xp[k], i0, i1);
        a0 = dot4(i0, w, a0); a1 = dot4(i1, w, a1);
      }
#pragma unroll 8
      for (int k = 0; k < Hsz / 4; ++k) {
        h4 w = whh0[k * G4 + tid];
        h4 i0, i1; split8(hp0[k], i0, i1);
        a0 = dot4(i0, w, a0); a1 = dot4(i1, w, a1);
      }
      g[0][tid] = a0; g[1][tid] = a1;
    }
    __syncthreads();
    if (tid < RPW * Hsz) {  // layer0 cell update (fp32)
      int r = tid >> 7, j = tid & (Hsz - 1);
      float ig = sigm(g[r][j]);
      float fg = sigm(g[r][j + Hsz]);
      float gg = tanh_f(g[r][j + 2 * Hsz]);
      float og = sigm(g[r][j + 3 * Hsz]);
      float c = fg * c0s[r][j] + ig * gg;
      float h = og * tanh_f(c);
      c0s[r][j] = c; h0f[r][j] = h;
      ((_Float16*)hp0)[pidx(r, j)] = (_Float16)h;
    }
    __syncthreads();
    {  // layer1 gates
      float a0 = b1, a1 = b1;
#pragma unroll 8
      for (int k = 0; k < Hsz / 4; ++k) {
        h4 w = wih1[k * G4 + tid];
        h4 i0, i1; split8(hp0[k], i0, i1);
        a0 = dot4(i0, w, a0); a1 = dot4(i1, w, a1);
      }
#pragma unroll 8
      for (int k = 0; k < Hsz / 4; ++k) {
        h4 w = s_whh1[k * G4 + tid];
        h4 i0, i1; split8(hp1[k], i0, i1);
        a0 = dot4(i0, w, a0); a1 = dot4(i1, w, a1);
      }
      g[0][tid] = a0; g[1][tid] = a1;
    }
    __syncthreads();
    if (tid < RPW * Hsz) {  // layer1 cell update
      int r = tid >> 7, j = tid & (Hsz - 1);
      float ig = sigm(g[r][j]);
      float fg = sigm(g[r][j + Hsz]);
      float gg = tanh_f(g[r][j + 2 * Hsz]);
      float og = sigm(g[r][j + 3 * Hsz]);
      float c = fg * c1s[r][j] + ig * gg;
      float h = og * tanh_f(c);
      c1s[r][j] = c; h1f[r][j] = h;
      ((_Float16*)hp1)[pidx(r, j)] = (_Float16)h;
    }
    __syncthreads();
  }
  if (tid < RPW * Hsz) {
    int r = tid >> 7, j = tid & (Hsz - 1);
    int row = row0 + r;
    st[0 * Bsz * Hsz + row * Hsz + j] = h0f[r][j];
    st[1 * Bsz * Hsz + row * Hsz + j] = c0s[r][j];
    st[2 * Bsz * Hsz + row * Hsz + j] = h1f[r][j];
    st[3 * Bsz * Hsz + row * Hsz + j] = c1s[r][j];
  }
}

__global__ void __launch_bounds__(NT, 1)
dec_kernel(const h4* __restrict__ wih0, const h4* __restrict__ whh0,
           const h4* __restrict__ wih1, const h4* __restrict__ whh1,
           const h4* __restrict__ fcp,
           const float* __restrict__ bsum0, const float* __restrict__ bsum1,
           const float* __restrict__ fcb, const float* __restrict__ st,
           float* __restrict__ out) {
  __shared__ h4 s_whh1[32 * G4];
  __shared__ float g[RPW][G4];
  __shared__ float c0s[RPW][Hsz], c1s[RPW][Hsz];
  __shared__ h8 hp0[Hsz / 4], hp1[Hsz / 4], yp[Dsz / 4];

  const int tid = threadIdx.x;
  const int row0 = blockIdx.x * RPW;

  for (int i = tid; i < 32 * G4; i += NT) s_whh1[i] = whh1[i];
  if (tid < RPW * Hsz) {
    int r = tid >> 7, j = tid & (Hsz - 1);
    int row = row0 + r;
    float h0v = st[0 * Bsz * Hsz + row * Hsz + j];
    c0s[r][j] = st[1 * Bsz * Hsz + row * Hsz + j];
    float h1v = st[2 * Bsz * Hsz + row * Hsz + j];
    c1s[r][j] = st[3 * Bsz * Hsz + row * Hsz + j];
    ((_Float16*)hp0)[pidx(r, j)] = (_Float16)h0v;
    ((_Float16*)hp1)[pidx(r, j)] = (_Float16)h1v;
  }
  if (tid < RPW * Dsz) ((_Float16*)yp)[tid] = (_Float16)0.f;  // y_init = zeros
  const float b0 = bsum0[tid];
  const float b1 = bsum1[tid];
  const float fb = (tid < RPW * Dsz) ? fcb[tid & (Dsz - 1)] : 0.f;
  __syncthreads();

  for (int t = 0; t < Ssz; ++t) {
    {  // dec cell0 gates (input = fed-back pred)
      float a0 = b0, a1 = b0;
#pragma unroll
      for (int k = 0; k < Dsz / 4; ++k) {
        h4 w = wih0[k * G4 + tid];
        h4 i0, i1; split8(yp[k], i0, i1);
        a0 = dot4(i0, w, a0); a1 = dot4(i1, w, a1);
      }
#pragma unroll 8
      for (int k = 0; k < Hsz / 4; ++k) {
        h4 w = whh0[k * G4 + tid];
        h4 i0, i1; split8(hp0[k], i0, i1);
        a0 = dot4(i0, w, a0); a1 = dot4(i1, w, a1);
      }
      g[0][tid] = a0; g[1][tid] = a1;
    }
    __syncthreads();
    if (tid < RPW * Hsz) {
      int r = tid >> 7, j = tid & (Hsz - 1);
      float ig = sigm(g[r][j]);
      float fg = sigm(g[r][j + Hsz]);
      float gg = tanh_f(g[r][j + 2 * Hsz]);
      float og = sigm(g[r][j + 3 * Hsz]);
      float c = fg * c0s[r][j] + ig * gg;
      float h = og * tanh_f(c);
      c0s[r][j] = c;
      ((_Float16*)hp0)[pidx(r, j)] = (_Float16)h;
    }
    __syncthreads();
    {  // dec cell1 gates
      float a0 = b1, a1 = b1;
#pragma unroll 8
      for (int k = 0; k < Hsz / 4; ++k) {
        h4 w = wih1[k * G4 + tid];
        h4 i0, i1; split8(hp0[k], i0, i1);
        a0 = dot4(i0, w, a0); a1 = dot4(i1, w, a1);
      }
#pragma unroll 8
      for (int k = 0; k < Hsz / 4; ++k) {
        h4 w = s_whh1[k * G4 + tid];
        h4 i0, i1; split8(hp1[k], i0, i1);
        a0 = dot4(i0, w, a0); a1 = dot4(i1, w, a1);
      }
      g[0][tid] = a0; g[1][tid] = a1;
    }
    __syncthreads();
    if (tid < RPW * Hsz) {
      int r = tid >> 7, j = tid & (Hsz - 1);
      float ig = sigm(g[r][j]);
      float fg = sigm(g[r][j + Hsz]);
      float gg = tanh_f(g[r][j + 2 * Hsz]);
      float og = sigm(g[r][j + 3 * Hsz]);
      float c = fg * c1s[r][j] + ig * gg;
      float h = og * tanh_f(c);
      c1s[r][j] = c;
      ((_Float16*)hp1)[pidx(r, j)] = (_Float16)h;
    }
    __syncthreads();
    if (tid < RPW * Dsz) {  // fc + write out + feedback
      int r = tid >> 6, j = tid & (Dsz - 1);
      float a = fb;
#pragma unroll 8
      for (int k = 0; k < Hsz / 4; ++k) {
        h4 i0, i1; split8(hp1[k], i0, i1);
        h4 w = fcp[k * Dsz + j];
        a = dot4(r == 0 ? i0 : i1, w, a);
      }
      out[((size_t)(row0 + r) * Ssz + t) * Dsz + j] = a;
      ((_Float16*)yp)[pidx(r, j)] = (_Float16)a;
    }
    __syncthreads();
  }
}

// Pack fp32 row-major [N][K] weight -> f16 k-major h4 [K/4][N]
__global__ void pack4_kernel(const float* __restrict__ W, h4* __restrict__ o, int K, int N) {
  int idx = blockIdx.x * 256 + threadIdx.x;
  int tot = (K >> 2) * N;
  if (idx >= tot) return;
  int k4 = idx / N, n = idx - k4 * N;
  const float* p = W + n * K + 4 * k4;
  h4 v;
  v[0] = (_Float16)p[0]; v[1] = (_Float16)p[1];
  v[2] = (_Float16)p[2]; v[3] = (_Float16)p[3];
  o[idx] = v;
}

__global__ void addb_kernel(const float* __restrict__ a, const float* __restrict__ b,
                            float* __restrict__ o, int n) {
  int i = blockIdx.x * 256 + threadIdx.x;
  if (i < n) o[i] = a[i] + b[i];
}

extern "C" void kernel_launch(void* const* d_in, const int* in_sizes, int n_in,
                              void* d_out, int out_size, void* d_ws, size_t ws_size,
                              hipStream_t stream) {
  (void)in_sizes; (void)n_in; (void)out_size; (void)ws_size;
  char* ws = (char*)d_ws;
  size_t off = 0;
  auto take = [&](size_t bytes) {
    char* p = ws + off;
    off += (bytes + 255) & ~(size_t)255;
    return p;
  };

  h4* e0_wih = (h4*)take(16 * 512 * 8);
  h4* e0_whh = (h4*)take(32 * 512 * 8);
  h4* e1_wih = (h4*)take(32 * 512 * 8);
  h4* e1_whh = (h4*)take(32 * 512 * 8);
  h4* d0_wih = (h4*)take(16 * 512 * 8);
  h4* d0_whh = (h4*)take(32 * 512 * 8);
  h4* d1_wih = (h4*)take(32 * 512 * 8);
  h4* d1_whh = (h4*)take(32 * 512 * 8);
  h4* fcp    = (h4*)take(32 * 64 * 8);
  float* bs_e0 = (float*)take(512 * 4);
  float* bs_e1 = (float*)take(512 * 4);
  float* bs_d0 = (float*)take(512 * 4);
  float* bs_d1 = (float*)take(512 * 4);
  float* st    = (float*)take(4 * Bsz * Hsz * 4);

  const float* x = (const float*)d_in[0];

  struct PW { const float* w; h4* o; int K, N; };
  PW pw[9] = {
    {(const float*)d_in[1],  e0_wih, 64, 512},
    {(const float*)d_in[2],  e0_whh, 128, 512},
    {(const float*)d_in[5],  e1_wih, 128, 512},
    {(const float*)d_in[6],  e1_whh, 128, 512},
    {(const float*)d_in[9],  d0_wih, 64, 512},
    {(const float*)d_in[10], d0_whh, 128, 512},
    {(const float*)d_in[13], d1_wih, 128, 512},
    {(const float*)d_in[14], d1_whh, 128, 512},
    {(const float*)d_in[17], fcp, 128, 64},
  };
  for (int i = 0; i < 9; ++i) {
    int tot = (pw[i].K >> 2) * pw[i].N;
    pack4_kernel<<<(tot + 255) / 256, 256, 0, stream>>>(pw[i].w, pw[i].o, pw[i].K, pw[i].N);
  }
  addb_kernel<<<2, 256, 0, stream>>>((const float*)d_in[3],  (const float*)d_in[4],  bs_e0, 512);
  addb_kernel<<<2, 256, 0, stream>>>((const float*)d_in[7],  (const float*)d_in[8],  bs_e1, 512);
  addb_kernel<<<2, 256, 0, stream>>>((const float*)d_in[11], (const float*)d_in[12], bs_d0, 512);
  addb_kernel<<<2, 256, 0, stream>>>((const float*)d_in[15], (const float*)d_in[16], bs_d1, 512);

  enc_kernel<<<NWG, NT, 0, stream>>>(x, e0_wih, e0_whh, e1_wih, e1_whh, bs_e0, bs_e1, st);
  dec_kernel<<<NWG, NT, 0, stream>>>(d0_wih, d0_whh, d1_wih, d1_whh, fcp, bs_d0, bs_d1,
                                     (const float*)d_in[18], st, (float*)d_out);
}

// Round 2
// 2339.008 us; speedup vs baseline: 2.7198x; 2.7198x over previous
//
#include <hip/hip_runtime.h>
#include <hip/hip_fp16.h>

// LSTM autoencoder: B=256, S=512, D=64, H=128.
// 1 row per WG, 256 WGs (one per CU). 512 threads = 512 gate columns.
// Weights: Wih0/Whh0/Wih1 columns in REGISTERS (h8, fully unrolled static
// indexing); Whh1 (128KB) + fc (16KB) in LDS. Zero per-step global reads.
// fp32 cell state in registers; f16 operands via LDS broadcast.

typedef _Float16 h2 __attribute__((ext_vector_type(2)));
typedef _Float16 h8 __attribute__((ext_vector_type(8)));

#define Bsz 256
#define Ssz 512
#define Dsz 64
#define Hsz 128
#define G4 512   // 4*H gate columns
#define NT 512   // threads per WG

__device__ __forceinline__ float fdot2f(h2 a, h2 b, float c) {
#if __has_builtin(__builtin_amdgcn_fdot2)
  return __builtin_amdgcn_fdot2(a, b, c, false);
#else
  return c + (float)a[0] * (float)b[0] + (float)a[1] * (float)b[1];
#endif
}

__device__ __forceinline__ float dot8(h8 v, h8 w, float acc) {
  h2 v0 = __builtin_shufflevector(v, v, 0, 1);
  h2 v1 = __builtin_shufflevector(v, v, 2, 3);
  h2 v2 = __builtin_shufflevector(v, v, 4, 5);
  h2 v3 = __builtin_shufflevector(v, v, 6, 7);
  h2 w0 = __builtin_shufflevector(w, w, 0, 1);
  h2 w1 = __builtin_shufflevector(w, w, 2, 3);
  h2 w2 = __builtin_shufflevector(w, w, 4, 5);
  h2 w3 = __builtin_shufflevector(w, w, 6, 7);
  acc = fdot2f(v0, w0, acc);
  acc = fdot2f(v1, w1, acc);
  acc = fdot2f(v2, w2, acc);
  acc = fdot2f(v3, w3, acc);
  return acc;
}

__device__ __forceinline__ float sigm(float v) { return 1.f / (1.f + __expf(-v)); }
__device__ __forceinline__ float tanh_f(float v) { return 2.f / (1.f + __expf(-2.f * v)) - 1.f; }

__global__ void __launch_bounds__(NT, 2)
enc_kernel(const float* __restrict__ x,
           const h8* __restrict__ wih0, const h8* __restrict__ whh0,
           const h8* __restrict__ wih1, const h8* __restrict__ whh1,
           const float* __restrict__ bsum0, const float* __restrict__ bsum1,
           float* __restrict__ st) {
  __shared__ h8 s_whh1[16 * G4];          // 128 KiB
  __shared__ float g[G4];                 // transposed gate scratch
  __shared__ h8 hp0[16], hp1[16];         // h as f16
  __shared__ h8 xp[2][8];                 // double-buffered x_t as f16

  const int tid = threadIdx.x;
  const int row = blockIdx.x;

  h8 Wih0[8], Whh0[16], Wih1[16];
#pragma unroll
  for (int k = 0; k < 8; ++k) Wih0[k] = wih0[k * G4 + tid];
#pragma unroll
  for (int k = 0; k < 16; ++k) Whh0[k] = whh0[k * G4 + tid];
#pragma unroll
  for (int k = 0; k < 16; ++k) Wih1[k] = wih1[k * G4 + tid];
  for (int i = tid; i < 16 * G4; i += NT) s_whh1[i] = whh1[i];

  if (tid < 128) ((_Float16*)hp0)[tid] = (_Float16)0.f;
  else if (tid < 256) ((_Float16*)hp1)[tid - 128] = (_Float16)0.f;
  else if (tid < 320) {
    int j = tid - 256;
    ((_Float16*)xp[0])[j] = (_Float16)x[(size_t)row * Ssz * Dsz + j];
  }
  const float b0 = bsum0[tid];
  const float b1 = bsum1[tid];
  float c_reg = 0.f, h_last = 0.f;
  __syncthreads();

  for (int t = 0; t < Ssz; ++t) {
    {  // P1: layer0 gates (x @ Wih0 + h0 @ Whh0)
      float a[4] = {b0, 0.f, 0.f, 0.f};
#pragma unroll
      for (int k = 0; k < 8; ++k) a[k & 3] = dot8(xp[t & 1][k], Wih0[k], a[k & 3]);
#pragma unroll
      for (int k = 0; k < 16; ++k) a[k & 3] = dot8(hp0[k], Whh0[k], a[k & 3]);
      g[4 * (tid & 127) + (tid >> 7)] = (a[0] + a[1]) + (a[2] + a[3]);
    }
    __syncthreads();
    if (tid < 128) {  // P2: layer0 cell update (c in reg)
      const float4 gv = *(const float4*)&g[4 * tid];
      float ig = sigm(gv.x), fg = sigm(gv.y), gg = tanh_f(gv.z), og = sigm(gv.w);
      c_reg = fg * c_reg + ig * gg;
      float h = og * tanh_f(c_reg);
      h_last = h;
      ((_Float16*)hp0)[tid] = (_Float16)h;
    } else if (tid >= 256 && tid < 320) {  // prefetch x(t+1)
      if (t + 1 < Ssz) {
        int j = tid - 256;
        ((_Float16*)xp[(t + 1) & 1])[j] =
            (_Float16)x[((size_t)row * Ssz + (t + 1)) * Dsz + j];
      }
    }
    __syncthreads();
    {  // P3: layer1 gates (h0 @ Wih1 + h1 @ Whh1)
      float a[4] = {b1, 0.f, 0.f, 0.f};
#pragma unroll
      for (int k = 0; k < 16; ++k) a[k & 3] = dot8(hp0[k], Wih1[k], a[k & 3]);
#pragma unroll
      for (int k = 0; k < 16; ++k) a[k & 3] = dot8(hp1[k], s_whh1[k * G4 + tid], a[k & 3]);
      g[4 * (tid & 127) + (tid >> 7)] = (a[0] + a[1]) + (a[2] + a[3]);
    }
    __syncthreads();
    if (tid >= 128 && tid < 256) {  // P4: layer1 cell update
      int j = tid - 128;
      const float4 gv = *(const float4*)&g[4 * j];
      float ig = sigm(gv.x), fg = sigm(gv.y), gg = tanh_f(gv.z), og = sigm(gv.w);
      c_reg = fg * c_reg + ig * gg;
      float h = og * tanh_f(c_reg);
      h_last = h;
      ((_Float16*)hp1)[j] = (_Float16)h;
    }
    __syncthreads();
  }

  if (tid < 128) {
    st[0 * Bsz * Hsz + row * Hsz + tid] = h_last;
    st[1 * Bsz * Hsz + row * Hsz + tid] = c_reg;
  } else if (tid < 256) {
    int j = tid - 128;
    st[2 * Bsz * Hsz + row * Hsz + j] = h_last;
    st[3 * Bsz * Hsz + row * Hsz + j] = c_reg;
  }
}

__global__ void __launch_bounds__(NT, 2)
dec_kernel(const h8* __restrict__ wih0, const h8* __restrict__ whh0,
           const h8* __restrict__ wih1, const h8* __restrict__ whh1,
           const h8* __restrict__ fcp,
           const float* __restrict__ bsum0, const float* __restrict__ bsum1,
           const float* __restrict__ fcb, const float* __restrict__ st,
           float* __restrict__ out) {
  __shared__ h8 s_whh1[16 * G4];          // 128 KiB
  __shared__ h8 s_fc[16 * Dsz];           // 16 KiB
  __shared__ float g[G4];
  __shared__ h8 hp0[16], hp1[16], yp[8];

  const int tid = threadIdx.x;
  const int row = blockIdx.x;

  h8 Wih0[8], Whh0[16], Wih1[16];
#pragma unroll
  for (int k = 0; k < 8; ++k) Wih0[k] = wih0[k * G4 + tid];
#pragma unroll
  for (int k = 0; k < 16; ++k) Whh0[k] = whh0[k * G4 + tid];
#pragma unroll
  for (int k = 0; k < 16; ++k) Wih1[k] = wih1[k * G4 + tid];
  for (int i = tid; i < 16 * G4; i += NT) s_whh1[i] = whh1[i];
  for (int i = tid; i < 16 * Dsz; i += NT) s_fc[i] = fcp[i];

  float c_reg = 0.f;
  if (tid < 128) {
    float h0v = st[0 * Bsz * Hsz + row * Hsz + tid];
    c_reg = st[1 * Bsz * Hsz + row * Hsz + tid];
    ((_Float16*)hp0)[tid] = (_Float16)h0v;
  } else if (tid < 256) {
    int j = tid - 128;
    float h1v = st[2 * Bsz * Hsz + row * Hsz + j];
    c_reg = st[3 * Bsz * Hsz + row * Hsz + j];
    ((_Float16*)hp1)[j] = (_Float16)h1v;
  } else if (tid < 320) {
    ((_Float16*)yp)[tid - 256] = (_Float16)0.f;  // y_init = zeros
  }
  const float b0 = bsum0[tid];
  const float b1 = bsum1[tid];
  const float fb = (tid < Dsz) ? fcb[tid] : 0.f;
  __syncthreads();

  for (int t = 0; t < Ssz; ++t) {
    {  // P1: dec cell0 gates (y @ Wih0 + h0 @ Whh0)
      float a[4] = {b0, 0.f, 0.f, 0.f};
#pragma unroll
      for (int k = 0; k < 8; ++k) a[k & 3] = dot8(yp[k], Wih0[k], a[k & 3]);
#pragma unroll
      for (int k = 0; k < 16; ++k) a[k & 3] = dot8(hp0[k], Whh0[k], a[k & 3]);
      g[4 * (tid & 127) + (tid >> 7)] = (a[0] + a[1]) + (a[2] + a[3]);
    }
    __syncthreads();
    if (tid < 128) {  // P2: cell0 update
      const float4 gv = *(const float4*)&g[4 * tid];
      float ig = sigm(gv.x), fg = sigm(gv.y), gg = tanh_f(gv.z), og = sigm(gv.w);
      c_reg = fg * c_reg + ig * gg;
      float h = og * tanh_f(c_reg);
      ((_Float16*)hp0)[tid] = (_Float16)h;
    }
    __syncthreads();
    {  // P3: cell1 gates (h0 @ Wih1 + h1 @ Whh1)
      float a[4] = {b1, 0.f, 0.f, 0.f};
#pragma unroll
      for (int k = 0; k < 16; ++k) a[k & 3] = dot8(hp0[k], Wih1[k], a[k & 3]);
#pragma unroll
      for (int k = 0; k < 16; ++k) a[k & 3] = dot8(hp1[k], s_whh1[k * G4 + tid], a[k & 3]);
      g[4 * (tid & 127) + (tid >> 7)] = (a[0] + a[1]) + (a[2] + a[3]);
    }
    __syncthreads();
    if (tid >= 128 && tid < 256) {  // P4: cell1 update
      int j = tid - 128;
      const float4 gv = *(const float4*)&g[4 * j];
      float ig = sigm(gv.x), fg = sigm(gv.y), gg = tanh_f(gv.z), og = sigm(gv.w);
      c_reg = fg * c_reg + ig * gg;
      float h = og * tanh_f(c_reg);
      ((_Float16*)hp1)[j] = (_Float16)h;
    }
    __syncthreads();
    if (tid < Dsz) {  // P5: fc + out + feedback
      float a[2] = {fb, 0.f};
#pragma unroll
      for (int k = 0; k < 16; ++k) a[k & 1] = dot8(hp1[k], s_fc[k * Dsz + tid], a[k & 1]);
      float v = a[0] + a[1];
      out[((size_t)row * Ssz + t) * Dsz + tid] = v;
      ((_Float16*)yp)[tid] = (_Float16)v;
    }
    __syncthreads();
  }
}

// Pack fp32 row-major [N][K] weight -> f16 k-major h8 [K/8][N]
__global__ void pack8_kernel(const float* __restrict__ W, h8* __restrict__ o, int K, int N) {
  int idx = blockIdx.x * 256 + threadIdx.x;
  int tot = (K >> 3) * N;
  if (idx >= tot) return;
  int k8 = idx / N, n = idx - k8 * N;
  const float* p = W + n * K + 8 * k8;
  h8 v;
#pragma unroll
  for (int j = 0; j < 8; ++j) v[j] = (_Float16)p[j];
  o[idx] = v;
}

__global__ void addb_kernel(const float* __restrict__ a, const float* __restrict__ b,
                            float* __restrict__ o, int n) {
  int i = blockIdx.x * 256 + threadIdx.x;
  if (i < n) o[i] = a[i] + b[i];
}

extern "C" void kernel_launch(void* const* d_in, const int* in_sizes, int n_in,
                              void* d_out, int out_size, void* d_ws, size_t ws_size,
                              hipStream_t stream) {
  (void)in_sizes; (void)n_in; (void)out_size; (void)ws_size;
  char* ws = (char*)d_ws;
  size_t off = 0;
  auto take = [&](size_t bytes) {
    char* p = ws + off;
    off += (bytes + 255) & ~(size_t)255;
    return p;
  };

  h8* e0_wih = (h8*)take(8 * 512 * 16);
  h8* e0_whh = (h8*)take(16 * 512 * 16);
  h8* e1_wih = (h8*)take(16 * 512 * 16);
  h8* e1_whh = (h8*)take(16 * 512 * 16);
  h8* d0_wih = (h8*)take(8 * 512 * 16);
  h8* d0_whh = (h8*)take(16 * 512 * 16);
  h8* d1_wih = (h8*)take(16 * 512 * 16);
  h8* d1_whh = (h8*)take(16 * 512 * 16);
  h8* fcp    = (h8*)take(16 * 64 * 16);
  float* bs_e0 = (float*)take(512 * 4);
  float* bs_e1 = (float*)take(512 * 4);
  float* bs_d0 = (float*)take(512 * 4);
  float* bs_d1 = (float*)take(512 * 4);
  float* st    = (float*)take(4 * Bsz * Hsz * 4);

  const float* x = (const float*)d_in[0];

  struct PW { const float* w; h8* o; int K, N; };
  PW pw[9] = {
    {(const float*)d_in[1],  e0_wih, 64, 512},
    {(const float*)d_in[2],  e0_whh, 128, 512},
    {(const float*)d_in[5],  e1_wih, 128, 512},
    {(const float*)d_in[6],  e1_whh, 128, 512},
    {(const float*)d_in[9],  d0_wih, 64, 512},
    {(const float*)d_in[10], d0_whh, 128, 512},
    {(const float*)d_in[13], d1_wih, 128, 512},
    {(const float*)d_in[14], d1_whh, 128, 512},
    {(const float*)d_in[17], fcp, 128, 64},
  };
  for (int i = 0; i < 9; ++i) {
    int tot = (pw[i].K >> 3) * pw[i].N;
    pack8_kernel<<<(tot + 255) / 256, 256, 0, stream>>>(pw[i].w, pw[i].o, pw[i].K, pw[i].N);
  }
  addb_kernel<<<2, 256, 0, stream>>>((const float*)d_in[3],  (const float*)d_in[4],  bs_e0, 512);
  addb_kernel<<<2, 256, 0, stream>>>((const float*)d_in[7],  (const float*)d_in[8],  bs_e1, 512);
  addb_kernel<<<2, 256, 0, stream>>>((const float*)d_in[11], (const float*)d_in[12], bs_d0, 512);
  addb_kernel<<<2, 256, 0, stream>>>((const float*)d_in[15], (const float*)d_in[16], bs_d1, 512);

  enc_kernel<<<Bsz, NT, 0, stream>>>(x, e0_wih, e0_whh, e1_wih, e1_whh, bs_e0, bs_e1, st);
  dec_kernel<<<Bsz, NT, 0, stream>>>(d0_wih, d0_whh, d1_wih, d1_whh, fcp, bs_d0, bs_d1,
                                     (const float*)d_in[18], st, (float*)d_out);
}